// Round 11
// baseline (167.018 us; speedup 1.0000x reference)
//
#include <hip/hip_runtime.h>

// Banded stereo cost volume via MFMA, all 3 scales in ONE launch.
// cost[j,h,x] = sum_c L[c,h,x]*R[c,h,x-j], 0 if x<j. C=32.
//
// Round-15: 512B-per-instruction stores (block-cooperative epilogue).
// r10 (D-split, acc 7x2, 4 blocks/CU) = 163.3us, kernel ~48us vs ~26-37us
// mixed-HBM floor. Last 2x-leverage hypothesis: since r9 the epilogue
// stores 8 lanes x 16B = 128B segments (8 scattered j-rows/inst); this
// problem's history shows sub-256B granularity write-amplifies (up to
// 8.6x) via L2 set thrash, and the r0/r4 scalar kernel with 512B/inst
// measured CLEAN WRITE_SIZE (121.8MB). r8->r9 never isolated store width.
// This round keeps r10's structure and swaps the epilogue back to the
// r8-verified block-cooperative gather: thread t stores j = j0+16jg+8r+
// (t>>5), x-run 4*(t&31) -> 32 lanes x 16B = 512B contiguous per j-row.
// Static indexing kept (no acc spill); tiles 17-padded (n*17+m); unioned
// into St (LDS 27.5KB, 4 blocks/CU); 13 barriers (r8 vs r9: ~free).
// Predict: WRITE ~115MB clean, kernel -> ~37-41us, dur_us ~152-156.
// Flat => writes already clean => mixed-BW floor reached.
//
// Core (verified r5-r10, absmax 0.25): per h, C[x,x'] = sum_c L[c,x]*
// R[c,x'] on band 0<=x-x'<=D-1; K=32 = ONE v_mfma_f32_16x16x32_f16/tile.
// R staged zero-padded for x'<0 -> band zeros fall out of the matmul.
// Block = 96-j slice (scale0 split in 2): wave w m-tiles 2w,2w+1, 7
// n-tiles each. Staging: f16 rows stride 80B, chunk-XOR (row>>2)&3.

#define NBLK_TOTAL 2368
#define SRB 80          // staging row stride in BYTES
#define NRW 352         // staged rows: L 128 (x-x0) + R 224 (x'-GB)
#define EPT 272         // epilogue tile stride in floats (16 rows x 17)

typedef float vf4 __attribute__((ext_vector_type(4)));
typedef float f32x4 __attribute__((ext_vector_type(4)));
typedef _Float16 h4 __attribute__((ext_vector_type(4)));
typedef _Float16 h8 __attribute__((ext_vector_type(8)));

template<int DG>
__device__ __forceinline__ void epilogue_b(const f32x4 (&acc0)[7], const f32x4 (&acc1)[7],
                                           float* __restrict__ Ep, float* __restrict__ o,
                                           int H, int W, int h, int j0, int x0,
                                           int t, int lm, int kg, int q0)
{
    // Shared tiles: Ep[(mt*2+slot)*EPT + n*17 + m], mt 0..7 global.
    // jg consumes rel 6-jg (slot jg&1, deposited prev step) and 5-jg
    // (slot (jg+1)&1, deposited this step). All indices static post-unroll.
    const int dep = lm * 17 + 4 * kg;

    #pragma unroll
    for (int jg = 0; jg < DG; ++jg) {
        if (jg == 0) {               // rel 6 -> slot 0
            *(f32x4*)&Ep[((q0)     * 2 + 0) * EPT + dep] = acc0[6];
            *(f32x4*)&Ep[((q0 + 1) * 2 + 0) * EPT + dep] = acc1[6];
        }
        {                            // rel 5-jg -> slot (5-jg)&1
            const int slot = (5 - jg) & 1;
            *(f32x4*)&Ep[((q0)     * 2 + slot) * EPT + dep] = acc0[5 - jg];
            *(f32x4*)&Ep[((q0 + 1) * 2 + slot) * EPT + dep] = acc1[5 - jg];
        }
        __syncthreads();
        const int s6 = jg & 1;       // slot of rel 6-jg
        const int s5 = s6 ^ 1;       // slot of rel 5-jg
        #pragma unroll
        for (int r = 0; r < 2; ++r) {
            int jo = 8 * r + (t >> 5);        // 0..15
            int j  = j0 + 16 * jg + jo;
            int xs = 4 * (t & 31);            // 0..124: full 128-x block range
            int mt = xs >> 4;                 // global m-tile 0..7
            int mb = xs & 15;
            vf4 v;
            #pragma unroll
            for (int i = 0; i < 4; ++i) {
                int m = mb + i;                    // <= 15
                int slot = (m >= jo) ? s6 : s5;
                int n = (m - jo) & 15;
                v[i] = Ep[(mt * 2 + slot) * EPT + n * 17 + m];
            }
            // 32 lanes x 16B = 512B contiguous per j-row per instruction.
            float* p = o + ((size_t)j * H + h) * W + x0 + xs;
            __builtin_nontemporal_store(v, (vf4*)p);
        }
        if (jg + 1 < DG) __syncthreads();   // protect slots before overwrite
    }
}

__global__ __launch_bounds__(256, 4)
void cost_volume_fused(const float* __restrict__ L0, const float* __restrict__ R0,
                       const float* __restrict__ L1, const float* __restrict__ R1,
                       const float* __restrict__ L2, const float* __restrict__ R2,
                       float* __restrict__ out)
{
    // Staging: 352 rows x 80 B = 27.5 KB. Epilogue tiles (17.0 KB) are
    // UNIONED into this space (St dead after frag reads; barrier between).
    __shared__ __align__(16) char St[NRW * SRB];

    // XCD-chunked bijective swizzle: 2368 = 8 * 296.
    const int id = (blockIdx.x & 7) * 296 + (blockIdx.x >> 3);

    const float* L; const float* R; float* o;
    int H, W, bx, h, j0, DG;
    if (id < 2048) {            // scale 0: H=256 W=512 D=192; 2 j-halves
        L = L0; R = R0; o = out;
        H = 256; W = 512;
        j0 = (id & 1) * 96; bx = (id >> 1) & 3; h = id >> 3; DG = 6;
    } else if (id < 2304) {     // scale 1: H=128 W=256 D=96
        int r = id - 2048;
        L = L1; R = R1; o = out + (size_t)192 * 256 * 512;
        H = 128; W = 256;
        j0 = 0; bx = r & 1; h = r >> 1; DG = 6;
    } else {                    // scale 2: H=64 W=128 D=48
        int r = id - 2304;
        L = L2; R = R2; o = out + (size_t)192 * 256 * 512 + (size_t)96 * 128 * 256;
        H = 64; W = 128;
        j0 = 0; bx = 0; h = r; DG = 3;
    }

    const int x0 = bx * 128;
    const int GB = x0 - j0 - 96;      // x' of R row 0 (may be <0 -> zero rows)
    const int t  = threadIdx.x;
    const int l  = t & 63;
    const int w_ = t >> 6;

    const size_t HW = (size_t)H * W;
    const float* Lb = L + (size_t)h * W;
    const float* Rb = R + (size_t)h * W;

    char* Sb = (char*)St;

    // ---- stage L: 256 items = (c4, x4); 4x4 reg transpose, f32 -> f16 ----
    {
        const int c0 = (t >> 5) * 4;
        const int x4 = t & 31;
        const float* gp = Lb + (size_t)c0 * HW + x0 + 4 * x4;
        vf4 v0 = *(const vf4*)(gp);
        vf4 v1 = *(const vf4*)(gp + HW);
        vf4 v2 = *(const vf4*)(gp + 2 * HW);
        vf4 v3 = *(const vf4*)(gp + 3 * HW);
        const int chk = (((c0 >> 3) ^ (x4 & 3)) << 4) | ((c0 & 7) << 1);
        #pragma unroll
        for (int xi = 0; xi < 4; ++xi) {
            int row = 4 * x4 + xi;            // (row>>2)&3 == x4&3
            h4 hv = { (_Float16)v0[xi], (_Float16)v1[xi],
                      (_Float16)v2[xi], (_Float16)v3[xi] };
            *(h4*)(Sb + row * SRB + chk) = hv;
        }
    }
    // ---- stage R: 448 items = 8 c4-groups x 56 x4; x' = GB + 4*x4 ----
    #pragma unroll
    for (int k = 0; k < 2; ++k) {
        int idm = t + k * 256;
        if (idm < 448) {
            int c0 = (idm / 56) * 4;
            int x4 = idm - (idm / 56) * 56;
            int g = GB + 4 * x4;
            vf4 v0 = (vf4)(0.f), v1 = (vf4)(0.f), v2 = (vf4)(0.f), v3 = (vf4)(0.f);
            if (g >= 0) {   // g+3 <= W-1 by construction at every scale
                const float* gp = Rb + (size_t)c0 * HW + g;
                v0 = *(const vf4*)(gp);
                v1 = *(const vf4*)(gp + HW);
                v2 = *(const vf4*)(gp + 2 * HW);
                v3 = *(const vf4*)(gp + 3 * HW);
            }
            const int chk = (((c0 >> 3) ^ (x4 & 3)) << 4) | ((c0 & 7) << 1);
            #pragma unroll
            for (int xi = 0; xi < 4; ++xi) {
                int row = 128 + 4 * x4 + xi;   // (row>>2)&3 == x4&3 (128%16==0)
                h4 hv = { (_Float16)v0[xi], (_Float16)v1[xi],
                          (_Float16)v2[xi], (_Float16)v3[xi] };
                *(h4*)(Sb + row * SRB + chk) = hv;
            }
        }
    }
    __syncthreads();

    // ---- MFMA: wave w -> m-tiles q0=2w, q0+1; 7 n-tiles (rel 0..6) ----
    const int lm = l & 15;
    const int kg = l >> 4;
    const int q0 = 2 * w_;
    const int rsw = (lm >> 2) & 3;        // (row>>2)&3 for rows 16q+lm

    f32x4 acc0[7], acc1[7];
    #pragma unroll
    for (int i = 0; i < 7; ++i) { acc0[i] = (f32x4)(0.f); acc1[i] = (f32x4)(0.f); }

    const int rowA0 = 16 * q0 + lm;
    const int rowA1 = rowA0 + 16;
    h8 a0 = *(const h8*)(Sb + rowA0 * SRB + ((kg ^ rsw) << 4));
    h8 a1 = *(const h8*)(Sb + rowA1 * SRB + ((kg ^ rsw) << 4));

    #pragma unroll
    for (int nt = 0; nt <= 7; ++nt) {
        int rowB = 128 + 16 * (q0 + nt) + lm;     // max 128+16*13+15 = 351
        h8 b = *(const h8*)(Sb + rowB * SRB + ((kg ^ rsw) << 4));
        if (nt <= 6)
            acc0[nt] = __builtin_amdgcn_mfma_f32_16x16x32_f16(a0, b, acc0[nt], 0, 0, 0);
        if (nt >= 1)
            acc1[nt - 1] = __builtin_amdgcn_mfma_f32_16x16x32_f16(a1, b, acc1[nt - 1], 0, 0, 0);
    }

    __syncthreads();   // all frag reads done -> St reusable as epilogue space

    // ---- epilogue: block-cooperative, 512B/inst stores, static DG ----
    float* Ep = (float*)St;
    if (DG == 6) epilogue_b<6>(acc0, acc1, Ep, o, H, W, h, j0, x0, t, lm, kg, q0);
    else         epilogue_b<3>(acc0, acc1, Ep, o, H, W, h, j0, x0, t, lm, kg, q0);
}

extern "C" void kernel_launch(void* const* d_in, const int* in_sizes, int n_in,
                              void* d_out, int out_size, void* d_ws, size_t ws_size,
                              hipStream_t stream)
{
    const float* L0 = (const float*)d_in[0];
    const float* R0 = (const float*)d_in[1];
    const float* L1 = (const float*)d_in[2];
    const float* R1 = (const float*)d_in[3];
    const float* L2 = (const float*)d_in[4];
    const float* R2 = (const float*)d_in[5];
    float* out = (float*)d_out;

    cost_volume_fused<<<dim3(NBLK_TOTAL), dim3(256), 0, stream>>>(
        L0, R0, L1, R1, L2, R2, out);
}